// Round 1
// baseline (379.676 us; speedup 1.0000x reference)
//
#include <hip/hip_runtime.h>

#define TOKENS 16384
#define KDIM   2048
#define NEXP   64
#define TOPK   6

// Kernel 1: partial GEMM. Grid (64 token-tiles, ns K-chunks), block 256.
// Lane layout: eg = lane&7 -> experts eg*8..eg*8+7 ; tg = lane>>3 -> 8 tokens.
// Each lane: acc[8 tokens][8 experts], per 4-k step 16 dwordx4 loads vs 256 FMAs.
__global__ __launch_bounds__(256, 2)
void moe_gemm_part(const float* __restrict__ x, const float* __restrict__ wg,
                   float* __restrict__ part, int Kc) {
  const int lane = threadIdx.x & 63;
  const int wid  = threadIdx.x >> 6;
  const int tg   = lane >> 3;
  const int eg   = lane & 7;
  const int row0 = blockIdx.x * 256 + wid * 64 + tg * 8;
  const int e0   = eg * 8;
  const int k0   = blockIdx.y * Kc;

  float acc[8][8];
#pragma unroll
  for (int i = 0; i < 8; ++i)
#pragma unroll
    for (int j = 0; j < 8; ++j) acc[i][j] = 0.f;

  const float* xp = x  + (size_t)row0 * KDIM + k0;
  const float* wp = wg + (size_t)k0 * NEXP + e0;

  for (int k = 0; k < Kc; k += 4) {
    float4 xv[8];
#pragma unroll
    for (int i = 0; i < 8; ++i)
      xv[i] = *(const float4*)(xp + (size_t)i * KDIM + k);

    float4 wa[4], wb[4];
#pragma unroll
    for (int d = 0; d < 4; ++d) {
      const float* wr = wp + (size_t)(k + d) * NEXP;
      wa[d] = *(const float4*)(wr);
      wb[d] = *(const float4*)(wr + 4);
    }

#pragma unroll
    for (int i = 0; i < 8; ++i) {
#pragma unroll
      for (int d = 0; d < 4; ++d) {
        const float xs = (d == 0) ? xv[i].x : (d == 1) ? xv[i].y
                       : (d == 2) ? xv[i].z : xv[i].w;
        acc[i][0] += xs * wa[d].x;
        acc[i][1] += xs * wa[d].y;
        acc[i][2] += xs * wa[d].z;
        acc[i][3] += xs * wa[d].w;
        acc[i][4] += xs * wb[d].x;
        acc[i][5] += xs * wb[d].y;
        acc[i][6] += xs * wb[d].z;
        acc[i][7] += xs * wb[d].w;
      }
    }
  }

  // part[ks][token][expert], fp32; every element written exactly once.
  float* pp = part + ((size_t)blockIdx.y * TOKENS + row0) * NEXP + e0;
#pragma unroll
  for (int i = 0; i < 8; ++i) {
    *(float4*)(pp + (size_t)i * NEXP)     = make_float4(acc[i][0], acc[i][1], acc[i][2], acc[i][3]);
    *(float4*)(pp + (size_t)i * NEXP + 4) = make_float4(acc[i][4], acc[i][5], acc[i][6], acc[i][7]);
  }
}

// Kernel 2: one wave per token. lane = expert. Sum ns partials, softmax,
// then 6 rounds of wave-argmax with jax tie-break (equal score -> lower idx).
// Output layout: out[0 .. 98303] = indices (as float), out[98304 ..] = scores.
__global__ __launch_bounds__(256)
void moe_softmax_topk(const float* __restrict__ part, float* __restrict__ out, int ns) {
  const int lane  = threadIdx.x & 63;
  const int wid   = threadIdx.x >> 6;
  const int token = blockIdx.x * 4 + wid;

  float logit = 0.f;
  for (int ks = 0; ks < ns; ++ks)
    logit += part[((size_t)ks * TOKENS + token) * NEXP + lane];

  // softmax (matches jax.nn.softmax: exp(x - max) / sum)
  float m = logit;
#pragma unroll
  for (int off = 32; off; off >>= 1) m = fmaxf(m, __shfl_xor(m, off));
  const float p = expf(logit - m);
  float s = p;
#pragma unroll
  for (int off = 32; off; off >>= 1) s += __shfl_xor(s, off);
  const float score = p / s;

  // iterative top-6 argmax; scores > 0 so -1 marks "taken"
  float v = score;
  int   idx = lane;
  float myv = 0.f;
  int   myi = 0;
#pragma unroll
  for (int r = 0; r < TOPK; ++r) {
    float bv = v;
    int   bi = idx;
#pragma unroll
    for (int off = 32; off; off >>= 1) {
      const float ov = __shfl_xor(bv, off);
      const int   oi = __shfl_xor(bi, off);
      if (ov > bv || (ov == bv && oi < bi)) { bv = ov; bi = oi; }
    }
    if (lane == r) { myv = bv; myi = bi; }
    if (idx == bi) v = -1.f;  // remove winner
  }

  if (lane < TOPK) {
    out[(size_t)token * TOPK + lane] = (float)myi;
    out[(size_t)TOKENS * TOPK + (size_t)token * TOPK + lane] = myv;
  }
}

extern "C" void kernel_launch(void* const* d_in, const int* in_sizes, int n_in,
                              void* d_out, int out_size, void* d_ws, size_t ws_size,
                              hipStream_t stream) {
  const float* x  = (const float*)d_in[0];
  const float* wg = (const float*)d_in[1];
  float* out  = (float*)d_out;
  float* part = (float*)d_ws;

  // pick largest K-split whose partial slab fits in ws
  int ns = 8;
  while (ns > 1 && (size_t)ns * TOKENS * NEXP * sizeof(float) > ws_size) ns >>= 1;
  const int Kc = KDIM / ns;

  dim3 g1(TOKENS / 256, ns);
  moe_gemm_part<<<g1, dim3(256), 0, stream>>>(x, wg, part, Kc);
  moe_softmax_topk<<<dim3(TOKENS / 4), dim3(256), 0, stream>>>(part, out, ns);
}

// Round 2
// 218.375 us; speedup vs baseline: 1.7386x; 1.7386x over previous
//
#include <hip/hip_runtime.h>

#define TOKENS 16384
#define KDIM   2048
#define NEXP   64
#define TOPK   6
#define BM     128
#define BK     32
#define XS     132   // xs row stride (floats): 528 B = 16B-aligned, non-pow2

// Kernel 1: LDS-tiled partial GEMM. Block 256 -> 128 tokens x 64 experts.
// Grid (128 token tiles, ns K-splits). Thread: 8 tok x 4 exp = 32 acc.
__global__ __launch_bounds__(256, 2)
void moe_gemm_tile(const float* __restrict__ x, const float* __restrict__ wg,
                   float* __restrict__ part, int Kc) {
  __shared__ float xs[BK * XS];     // transposed: xs[k][tok]
  __shared__ float ws[BK * NEXP];   // ws[k][expert]

  const int t    = threadIdx.x;
  const int row0 = blockIdx.x * BM;
  const int k0   = blockIdx.y * Kc;

  const int eg = t & 15;   // experts eg*4..+3
  const int tg = t >> 4;   // tokens  tg*8..+7

  const int lrow = t >> 3; // staging: row within 32-row pass
  const int c4   = t & 7;  // staging: float4 column (k-offset c4*4)

  float acc[8][4];
#pragma unroll
  for (int i = 0; i < 8; ++i)
#pragma unroll
    for (int j = 0; j < 4; ++j) acc[i][j] = 0.f;

  for (int kk = 0; kk < Kc; kk += BK) {
    // stage x[row0..+127][k0+kk..+31] -> xs transposed
    const float* xg = x + (size_t)row0 * KDIM + k0 + kk;
#pragma unroll
    for (int r = 0; r < 4; ++r) {
      const int row = lrow + r * 32;
      float4 f = *(const float4*)(xg + (size_t)row * KDIM + c4 * 4);
      xs[(c4 * 4 + 0) * XS + row] = f.x;
      xs[(c4 * 4 + 1) * XS + row] = f.y;
      xs[(c4 * 4 + 2) * XS + row] = f.z;
      xs[(c4 * 4 + 3) * XS + row] = f.w;
    }
    // stage w[k0+kk..+31][0..63] -> ws (contiguous 8 KB)
    const float* wp = wg + (size_t)(k0 + kk) * NEXP;
    *(float4*)(ws + t * 8)     = *(const float4*)(wp + t * 8);
    *(float4*)(ws + t * 8 + 4) = *(const float4*)(wp + t * 8 + 4);
    __syncthreads();

#pragma unroll 4
    for (int k = 0; k < BK; ++k) {
      const float4 x0 = *(const float4*)(xs + k * XS + tg * 8);
      const float4 x1 = *(const float4*)(xs + k * XS + tg * 8 + 4);
      const float4 w0 = *(const float4*)(ws + k * NEXP + eg * 4);
      const float xv[8] = {x0.x, x0.y, x0.z, x0.w, x1.x, x1.y, x1.z, x1.w};
#pragma unroll
      for (int i = 0; i < 8; ++i) {
        acc[i][0] += xv[i] * w0.x;
        acc[i][1] += xv[i] * w0.y;
        acc[i][2] += xv[i] * w0.z;
        acc[i][3] += xv[i] * w0.w;
      }
    }
    __syncthreads();
  }

  // part[ks][token][expert]; lanes eg=0..15 -> 256B contiguous per tg
  float* pp = part + ((size_t)blockIdx.y * TOKENS + row0 + tg * 8) * NEXP + eg * 4;
#pragma unroll
  for (int i = 0; i < 8; ++i)
    *(float4*)(pp + (size_t)i * NEXP) =
        make_float4(acc[i][0], acc[i][1], acc[i][2], acc[i][3]);
}

// Kernel 2: 16 lanes per token, 4 experts/lane (float4 loads).
// Butterfly reductions within 16-lane groups; 6 argmax rounds with jax
// tie-break (equal score -> lower index). out: indices then scores.
__global__ __launch_bounds__(256)
void moe_softmax_topk(const float* __restrict__ part, float* __restrict__ out, int ns) {
  const int lane = threadIdx.x & 63;
  const int wid  = threadIdx.x >> 6;
  const int sub  = lane & 15;                      // expert group
  const int tok  = blockIdx.x * 16 + wid * 4 + (lane >> 4);

  float v[4] = {0.f, 0.f, 0.f, 0.f};
  for (int ks = 0; ks < ns; ++ks) {
    const float4 p = *(const float4*)(part + ((size_t)ks * TOKENS + tok) * NEXP + sub * 4);
    v[0] += p.x; v[1] += p.y; v[2] += p.z; v[3] += p.w;
  }

  // softmax over 64 experts (16 lanes x 4)
  float m = fmaxf(fmaxf(v[0], v[1]), fmaxf(v[2], v[3]));
#pragma unroll
  for (int off = 1; off < 16; off <<= 1) m = fmaxf(m, __shfl_xor(m, off));
  float p0 = expf(v[0] - m), p1 = expf(v[1] - m), p2 = expf(v[2] - m), p3 = expf(v[3] - m);
  float s = p0 + p1 + p2 + p3;
#pragma unroll
  for (int off = 1; off < 16; off <<= 1) s += __shfl_xor(s, off);
  v[0] = p0 / s; v[1] = p1 / s; v[2] = p2 / s; v[3] = p3 / s;

  float resv = 0.f; int resi = 0;
#pragma unroll
  for (int r = 0; r < TOPK; ++r) {
    float bv = v[0]; int bi = sub * 4;
#pragma unroll
    for (int j = 1; j < 4; ++j)
      if (v[j] > bv) { bv = v[j]; bi = sub * 4 + j; }   // strict > : lowest idx on tie
#pragma unroll
    for (int off = 1; off < 16; off <<= 1) {
      const float ov = __shfl_xor(bv, off);
      const int   oi = __shfl_xor(bi, off);
      if (ov > bv || (ov == bv && oi < bi)) { bv = ov; bi = oi; }
    }
    if (sub == r) { resv = bv; resi = bi; }
    if ((bi >> 2) == sub) v[bi & 3] = -1.f;   // scores > 0, sentinel safe
  }

  if (sub < TOPK) {
    out[(size_t)tok * TOPK + sub] = (float)resi;
    out[(size_t)TOKENS * TOPK + (size_t)tok * TOPK + sub] = resv;
  }
}

extern "C" void kernel_launch(void* const* d_in, const int* in_sizes, int n_in,
                              void* d_out, int out_size, void* d_ws, size_t ws_size,
                              hipStream_t stream) {
  const float* x  = (const float*)d_in[0];
  const float* wg = (const float*)d_in[1];
  float* out  = (float*)d_out;
  float* part = (float*)d_ws;

  int ns = 4;
  while (ns > 1 && (size_t)ns * TOKENS * NEXP * sizeof(float) > ws_size) ns >>= 1;
  const int Kc = KDIM / ns;

  dim3 g1(TOKENS / BM, ns);
  moe_gemm_tile<<<g1, dim3(256), 0, stream>>>(x, wg, part, Kc);
  moe_softmax_topk<<<dim3(TOKENS / 16), dim3(256), 0, stream>>>(part, out, ns);
}